// Round 1
// baseline (826.038 us; speedup 1.0000x reference)
//
#include <hip/hip_runtime.h>
#include <math.h>

#define TWO_PI 6.28318530717958647692f
#define PI_F   3.14159265358979323846f
#define NORM   0.0078125f  /* 1/sqrt(128*128) */

// ---------------------------------------------------------------- tables
__device__ __forceinline__ float kfreq(int i) { return (i <= 10) ? (float)i : (float)(i - 21); }

__global__ void k_tables(const float* __restrict__ thrx, const float* __restrict__ thrt,
                         float2* __restrict__ pc, float2* __restrict__ qx, float2* __restrict__ qt) {
    int t = threadIdx.x;
    for (int idx = t; idx < 21 * 128; idx += 256) {
        int i = idx >> 7, n = idx & 127;
        float k = kfreq(i), fn = (float)n;
        float s, c;
        // forward twiddle exp(-2pi i * k n / 128)  (identical for x and t axes)
        float ang = -TWO_PI * k * fn * (1.0f / 128.0f);
        sincosf(ang, &s, &c);
        pc[idx] = make_float2(c, s);
        // inverse complex-frequency twiddles
        {
            float raw = thrx[i];
            float sig = 1.0f / (1.0f + expf(-raw));
            float th = (k < 0.0f) ? (0.5f * PI_F) * (1.0f + sig) : PI_F * sig;
            float ka = fabsf(k);
            float amp = expf(-TWO_PI * ka * sinf(th) * fn * (1.0f / 128.0f));
            float a2 = TWO_PI * ka * cosf(th) * fn * (1.0f / 128.0f);
            sincosf(a2, &s, &c);
            qx[idx] = make_float2(amp * c, amp * s);
        }
        {
            float raw = thrt[i];
            float sig = 1.0f / (1.0f + expf(-raw));
            float th = (k < 0.0f) ? (0.5f * PI_F) * (1.0f + sig) : PI_F * sig;
            float ka = fabsf(k);
            float amp = expf(-TWO_PI * ka * sinf(th) * fn * (1.0f / 128.0f));
            float a2 = TWO_PI * ka * cosf(th) * fn * (1.0f / 128.0f);
            sincosf(a2, &s, &c);
            qt[idx] = make_float2(amp * c, amp * s);
        }
    }
}

// ---------------------------------------------------------------- weight repack
__global__ void k_repack(const float* __restrict__ wr, const float* __restrict__ wi,
                         float2* __restrict__ Rt) {
    int idx = blockIdx.x * 256 + threadIdx.x;  // exactly 64*64*441 threads
    if (idx >= 64 * 64 * 441) return;
    int ij = idx % 441;
    int co = idx / 441;
    Rt[(size_t)ij * 4096 + co] = make_float2(wr[idx], wi[idx]);
}

// ---------------------------------------------------------------- forward DFT (per b,c)
__launch_bounds__(256, 2)
__global__ void k_fwd(const float* __restrict__ x, const float2* __restrict__ pc,
                      float2* __restrict__ X) {
    __shared__ __align__(16) float  xs[128 * 36];   // 32-col chunk of x, padded
    __shared__ __align__(16) float2 pts[21 * 128];  // forward twiddle (t axis)
    __shared__ __align__(16) float2 t1s[21 * 130];  // T1[j][n]
    const int t = threadIdx.x;
    const int bc = blockIdx.x;

    {   // stage twiddle
        const float4* g4 = reinterpret_cast<const float4*>(pc);
        float4* s4 = reinterpret_cast<float4*>(pts);
        for (int k = t; k < 1344; k += 256) s4[k] = g4[k];
    }

    const int rg = t & 31;   // row group: rows rg + 32*r
    const int jg = t >> 5;   // 0..7
    const int jbase = (jg < 5) ? 3 * jg : 15 + 2 * (jg - 5);
    const int jcnt  = (jg < 5) ? 3 : 2;

    float are[4][3], aim[4][3];
    #pragma unroll
    for (int r = 0; r < 4; ++r)
        #pragma unroll
        for (int jj = 0; jj < 3; ++jj) { are[r][jj] = 0.f; aim[r][jj] = 0.f; }

    const float* xg = x + (size_t)bc * 16384;
    for (int ch = 0; ch < 4; ++ch) {
        __syncthreads();
        #pragma unroll
        for (int kk = 0; kk < 4; ++kk) {   // load 128x32 chunk
            int fid = kk * 256 + t;
            int n = fid >> 3, f = fid & 7;
            float4 v = *reinterpret_cast<const float4*>(xg + n * 128 + ch * 32 + f * 4);
            *reinterpret_cast<float4*>(&xs[n * 36 + f * 4]) = v;
        }
        __syncthreads();
        const float4* pts4 = reinterpret_cast<const float4*>(pts);
        #pragma unroll
        for (int mm = 0; mm < 8; ++mm) {
            float4 xv[4];
            #pragma unroll
            for (int r = 0; r < 4; ++r)
                xv[r] = *reinterpret_cast<const float4*>(&xs[(rg + 32 * r) * 36 + mm * 4]);
            int mbase = (ch * 8 + mm) * 2;
            #pragma unroll
            for (int jj = 0; jj < 3; ++jj) {
                if (jj < jcnt) {
                    int j = jbase + jj;
                    float4 A = pts4[j * 64 + mbase];
                    float4 B = pts4[j * 64 + mbase + 1];
                    #pragma unroll
                    for (int r = 0; r < 4; ++r) {
                        are[r][jj] += xv[r].x * A.x + xv[r].y * A.z + xv[r].z * B.x + xv[r].w * B.z;
                        aim[r][jj] += xv[r].x * A.y + xv[r].y * A.w + xv[r].z * B.y + xv[r].w * B.w;
                    }
                }
            }
        }
    }
    __syncthreads();
    #pragma unroll
    for (int jj = 0; jj < 3; ++jj) {
        if (jj < jcnt) {
            int j = jbase + jj;
            #pragma unroll
            for (int r = 0; r < 4; ++r)
                t1s[j * 130 + rg + 32 * r] = make_float2(are[r][jj], aim[r][jj]);
        }
    }
    __syncthreads();
    // phase 3: X[i][j] = sum_n px[i][n] * T1[n][j]
    const float4* t14 = reinterpret_cast<const float4*>(t1s);
    const float4* pc4 = reinterpret_cast<const float4*>(pc);
    for (int p = t; p < 441; p += 256) {
        int i = p / 21, j = p % 21;
        float accre = 0.f, accim = 0.f;
        #pragma unroll 4
        for (int n4 = 0; n4 < 32; ++n4) {
            float4 TA = t14[j * 65 + n4 * 2];
            float4 TB = t14[j * 65 + n4 * 2 + 1];
            float4 PA = pc4[i * 64 + n4 * 2];
            float4 PB = pc4[i * 64 + n4 * 2 + 1];
            accre += PA.x * TA.x - PA.y * TA.y;
            accim += PA.x * TA.y + PA.y * TA.x;
            accre += PA.z * TA.z - PA.w * TA.w;
            accim += PA.z * TA.w + PA.w * TA.z;
            accre += PB.x * TB.x - PB.y * TB.y;
            accim += PB.x * TB.y + PB.y * TB.x;
            accre += PB.z * TB.z - PB.w * TB.w;
            accim += PB.z * TB.w + PB.w * TB.z;
        }
        X[(size_t)p * 2048 + bc] = make_float2(accre * NORM, accim * NORM);
    }
}

// ---------------------------------------------------------------- channel mix (per mode)
__launch_bounds__(256, 2)
__global__ void k_mix(const float2* __restrict__ X, const float2* __restrict__ Rt,
                      float2* __restrict__ OK) {
    __shared__ float2 Xs[2048];
    __shared__ float2 Rs[4096];
    int t = threadIdx.x;
    int ij = blockIdx.x;
    for (int k = t; k < 2048; k += 256) Xs[k] = X[(size_t)ij * 2048 + k];
    for (int k = t; k < 4096; k += 256) Rs[k] = Rt[(size_t)ij * 4096 + k];
    __syncthreads();
    int o = t & 63, bg = t >> 6;
    float accre[8], accim[8];
    #pragma unroll
    for (int i = 0; i < 8; ++i) { accre[i] = 0.f; accim[i] = 0.f; }
    for (int c = 0; c < 64; ++c) {
        float2 rv = Rs[c * 64 + o];
        #pragma unroll
        for (int bb = 0; bb < 8; ++bb) {
            float2 xv = Xs[(bg * 8 + bb) * 64 + c];
            accre[bb] += xv.x * rv.x - xv.y * rv.y;
            accim[bb] += xv.x * rv.y + xv.y * rv.x;
        }
    }
    #pragma unroll
    for (int bb = 0; bb < 8; ++bb)
        OK[(size_t)ij * 2048 + (bg * 8 + bb) * 64 + o] = make_float2(accre[bb], accim[bb]);
}

// ---------------------------------------------------------------- inverse DFT (per b,o)
__launch_bounds__(256, 2)
__global__ void k_inv(const float2* __restrict__ OKg, const float2* __restrict__ qx,
                      const float2* __restrict__ qt, float* __restrict__ out) {
    __shared__ __align__(16) float2 qs[21 * 128];
    __shared__ __align__(16) float2 t2s[128 * 22];
    __shared__ float2 oks[441];
    const int t = threadIdx.x;
    const int bo = blockIdx.x;

    for (int k = t; k < 441; k += 256) oks[k] = OKg[(size_t)k * 2048 + bo];
    {
        const float4* g4 = reinterpret_cast<const float4*>(qx);
        float4* s4 = reinterpret_cast<float4*>(qs);
        for (int k = t; k < 1344; k += 256) s4[k] = g4[k];
    }
    __syncthreads();
    // phase A: T2[n][j] = sum_i ok[i][j] * qx[i][n]
    {
        const int ng = t & 31, jg = t >> 5;
        const int jbase = (jg < 5) ? 3 * jg : 15 + 2 * (jg - 5);
        const int jcnt  = (jg < 5) ? 3 : 2;
        float are[4][3], aim[4][3];
        #pragma unroll
        for (int r = 0; r < 4; ++r)
            #pragma unroll
            for (int jj = 0; jj < 3; ++jj) { are[r][jj] = 0.f; aim[r][jj] = 0.f; }
        const float4* qs4 = reinterpret_cast<const float4*>(qs);
        for (int i = 0; i < 21; ++i) {
            float4 QA = qs4[i * 64 + ng * 2];
            float4 QB = qs4[i * 64 + ng * 2 + 1];
            #pragma unroll
            for (int jj = 0; jj < 3; ++jj) {
                if (jj < jcnt) {
                    float2 okv = oks[i * 21 + jbase + jj];
                    are[0][jj] += okv.x * QA.x - okv.y * QA.y;
                    aim[0][jj] += okv.x * QA.y + okv.y * QA.x;
                    are[1][jj] += okv.x * QA.z - okv.y * QA.w;
                    aim[1][jj] += okv.x * QA.w + okv.y * QA.z;
                    are[2][jj] += okv.x * QB.x - okv.y * QB.y;
                    aim[2][jj] += okv.x * QB.y + okv.y * QB.x;
                    are[3][jj] += okv.x * QB.z - okv.y * QB.w;
                    aim[3][jj] += okv.x * QB.w + okv.y * QB.z;
                }
            }
        }
        #pragma unroll
        for (int jj = 0; jj < 3; ++jj) {
            if (jj < jcnt) {
                #pragma unroll
                for (int r = 0; r < 4; ++r)
                    t2s[(ng * 4 + r) * 22 + jbase + jj] = make_float2(are[r][jj], aim[r][jj]);
            }
        }
    }
    __syncthreads();
    {   // reload twiddle with qt
        const float4* g4 = reinterpret_cast<const float4*>(qt);
        float4* s4 = reinterpret_cast<float4*>(qs);
        for (int k = t; k < 1344; k += 256) s4[k] = g4[k];
    }
    __syncthreads();
    // phase B: out[n][m] = Re( sum_j T2[n][j] * qt[j][m] )
    {
        const int mg = t & 31, ng = t >> 5;
        const float4* qs4 = reinterpret_cast<const float4*>(qs);
        float* og = out + (size_t)bo * 16384;
        for (int nb = 0; nb < 4; ++nb) {
            int n0 = nb * 32 + ng * 4;
            float acc[4][4];
            #pragma unroll
            for (int r = 0; r < 4; ++r)
                #pragma unroll
                for (int m = 0; m < 4; ++m) acc[r][m] = 0.f;
            for (int j = 0; j < 21; ++j) {
                float4 QA = qs4[j * 64 + mg * 2];
                float4 QB = qs4[j * 64 + mg * 2 + 1];
                #pragma unroll
                for (int r = 0; r < 4; ++r) {
                    float2 t2v = t2s[(n0 + r) * 22 + j];
                    acc[r][0] += t2v.x * QA.x - t2v.y * QA.y;
                    acc[r][1] += t2v.x * QA.z - t2v.y * QA.w;
                    acc[r][2] += t2v.x * QB.x - t2v.y * QB.y;
                    acc[r][3] += t2v.x * QB.z - t2v.y * QB.w;
                }
            }
            #pragma unroll
            for (int r = 0; r < 4; ++r) {
                float4 v = make_float4(acc[r][0] * NORM, acc[r][1] * NORM,
                                       acc[r][2] * NORM, acc[r][3] * NORM);
                *reinterpret_cast<float4*>(og + (n0 + r) * 128 + mg * 4) = v;
            }
        }
    }
}

// ---------------------------------------------------------------- launch
extern "C" void kernel_launch(void* const* d_in, const int* in_sizes, int n_in,
                              void* d_out, int out_size, void* d_ws, size_t ws_size,
                              hipStream_t stream) {
    const float* x   = (const float*)d_in[0];
    const float* wr  = (const float*)d_in[1];
    const float* wi  = (const float*)d_in[2];
    const float* thx = (const float*)d_in[3];
    const float* tht = (const float*)d_in[4];
    float* out = (float*)d_out;

    char* ws = (char*)d_ws;
    float2* pc = (float2*)(ws);
    float2* qx = (float2*)(ws + 21504);
    float2* qt = (float2*)(ws + 43008);
    float2* Rt = (float2*)(ws + 64512);
    float2* X  = (float2*)(ws + 64512 + 14450688);
    float2* OK = (float2*)(ws + 64512 + 14450688 + 7225344);

    k_tables<<<1, 256, 0, stream>>>(thx, tht, pc, qx, qt);
    k_repack<<<7056, 256, 0, stream>>>(wr, wi, Rt);
    k_fwd<<<2048, 256, 0, stream>>>(x, pc, X);
    k_mix<<<441, 256, 0, stream>>>(X, Rt, OK);
    k_inv<<<2048, 256, 0, stream>>>(OK, qx, qt, out);
}

// Round 2
// 808.877 us; speedup vs baseline: 1.0212x; 1.0212x over previous
//
#include <hip/hip_runtime.h>
#include <math.h>

#define TWO_PI 6.28318530717958647692f
#define PI_F   3.14159265358979323846f
#define NORM   0.0078125f  /* 1/sqrt(128*128) */

// ---------------------------------------------------------------- tables
__device__ __forceinline__ float kfreq(int i) { return (i <= 10) ? (float)i : (float)(i - 21); }

__global__ void k_tables(const float* __restrict__ thrx, const float* __restrict__ thrt,
                         float2* __restrict__ pc, float2* __restrict__ qx, float2* __restrict__ qt) {
    int t = threadIdx.x;
    for (int idx = t; idx < 21 * 128; idx += 256) {
        int i = idx >> 7, n = idx & 127;
        float k = kfreq(i), fn = (float)n;
        float s, c;
        float ang = -TWO_PI * k * fn * (1.0f / 128.0f);
        sincosf(ang, &s, &c);
        pc[idx] = make_float2(c, s);
        {
            float raw = thrx[i];
            float sig = 1.0f / (1.0f + expf(-raw));
            float th = (k < 0.0f) ? (0.5f * PI_F) * (1.0f + sig) : PI_F * sig;
            float ka = fabsf(k);
            float amp = expf(-TWO_PI * ka * sinf(th) * fn * (1.0f / 128.0f));
            float a2 = TWO_PI * ka * cosf(th) * fn * (1.0f / 128.0f);
            sincosf(a2, &s, &c);
            qx[idx] = make_float2(amp * c, amp * s);
        }
        {
            float raw = thrt[i];
            float sig = 1.0f / (1.0f + expf(-raw));
            float th = (k < 0.0f) ? (0.5f * PI_F) * (1.0f + sig) : PI_F * sig;
            float ka = fabsf(k);
            float amp = expf(-TWO_PI * ka * sinf(th) * fn * (1.0f / 128.0f));
            float a2 = TWO_PI * ka * cosf(th) * fn * (1.0f / 128.0f);
            sincosf(a2, &s, &c);
            qt[idx] = make_float2(amp * c, amp * s);
        }
    }
}

// ---------------------------------------------------------------- weight transpose [co][ij] -> [ij][co]
__global__ void k_wt(const float* __restrict__ wr, const float* __restrict__ wi,
                     float2* __restrict__ Rt) {
    __shared__ float2 tile[64][65];
    const int tx = threadIdx.x & 63;
    const int ty = threadIdx.x >> 6;
    const int ij0 = blockIdx.x * 64;
    const int co0 = blockIdx.y * 64;
    #pragma unroll
    for (int r = 0; r < 16; ++r) {
        int row = ty + r * 4;            // co_local
        int col = ij0 + tx;              // ij
        if (col < 441) {
            size_t g = (size_t)(co0 + row) * 441 + col;
            tile[row][tx] = make_float2(wr[g], wi[g]);
        }
    }
    __syncthreads();
    #pragma unroll
    for (int r = 0; r < 16; ++r) {
        int row = ty + r * 4;            // ij_local
        int ij = ij0 + row;
        if (ij < 441)
            Rt[(size_t)ij * 4096 + co0 + tx] = tile[tx][row];
    }
}

// ---------------------------------------------------------------- forward DFT (per b,c)
// writes X in [bc][448] layout (contiguous per block)
__launch_bounds__(256, 2)
__global__ void k_fwd(const float* __restrict__ x, const float2* __restrict__ pc,
                      float2* __restrict__ Xb) {
    __shared__ __align__(16) char ubuf[21 * 130 * 8];  // union: xs (18432 B) / t1s (21840 B)
    __shared__ __align__(16) float2 pts[21 * 128];
    float*  xs  = reinterpret_cast<float*>(ubuf);
    float2* t1s = reinterpret_cast<float2*>(ubuf);
    const int t = threadIdx.x;
    const int bc = blockIdx.x;

    {   // stage twiddle
        const float4* g4 = reinterpret_cast<const float4*>(pc);
        float4* s4 = reinterpret_cast<float4*>(pts);
        for (int k = t; k < 1344; k += 256) s4[k] = g4[k];
    }

    const int rg = t & 31;
    const int jg = t >> 5;
    const int jbase = (jg < 5) ? 3 * jg : 15 + 2 * (jg - 5);
    const int jcnt  = (jg < 5) ? 3 : 2;

    float are[4][3], aim[4][3];
    #pragma unroll
    for (int r = 0; r < 4; ++r)
        #pragma unroll
        for (int jj = 0; jj < 3; ++jj) { are[r][jj] = 0.f; aim[r][jj] = 0.f; }

    const float* xg = x + (size_t)bc * 16384;
    for (int ch = 0; ch < 4; ++ch) {
        __syncthreads();
        #pragma unroll
        for (int kk = 0; kk < 4; ++kk) {
            int fid = kk * 256 + t;
            int n = fid >> 3, f = fid & 7;
            float4 v = *reinterpret_cast<const float4*>(xg + n * 128 + ch * 32 + f * 4);
            *reinterpret_cast<float4*>(&xs[n * 36 + f * 4]) = v;
        }
        __syncthreads();
        const float4* pts4 = reinterpret_cast<const float4*>(pts);
        #pragma unroll
        for (int mm = 0; mm < 8; ++mm) {
            float4 xv[4];
            #pragma unroll
            for (int r = 0; r < 4; ++r)
                xv[r] = *reinterpret_cast<const float4*>(&xs[(rg + 32 * r) * 36 + mm * 4]);
            int mbase = (ch * 8 + mm) * 2;
            #pragma unroll
            for (int jj = 0; jj < 3; ++jj) {
                if (jj < jcnt) {
                    int j = jbase + jj;
                    float4 A = pts4[j * 64 + mbase];
                    float4 B = pts4[j * 64 + mbase + 1];
                    #pragma unroll
                    for (int r = 0; r < 4; ++r) {
                        are[r][jj] += xv[r].x * A.x + xv[r].y * A.z + xv[r].z * B.x + xv[r].w * B.z;
                        aim[r][jj] += xv[r].x * A.y + xv[r].y * A.w + xv[r].z * B.y + xv[r].w * B.w;
                    }
                }
            }
        }
    }
    __syncthreads();   // xs dead beyond this point; ubuf becomes t1s
    #pragma unroll
    for (int jj = 0; jj < 3; ++jj) {
        if (jj < jcnt) {
            int j = jbase + jj;
            #pragma unroll
            for (int r = 0; r < 4; ++r)
                t1s[j * 130 + rg + 32 * r] = make_float2(are[r][jj], aim[r][jj]);
        }
    }
    __syncthreads();
    // phase 3: X[i][j] = sum_n px[i][n] * T1[n][j]; coalesced contiguous write
    const float4* t14 = reinterpret_cast<const float4*>(ubuf);
    const float4* pc4 = reinterpret_cast<const float4*>(pc);
    for (int p = t; p < 441; p += 256) {
        int i = p / 21, j = p % 21;
        float accre = 0.f, accim = 0.f;
        #pragma unroll 4
        for (int n4 = 0; n4 < 32; ++n4) {
            float4 TA = t14[j * 65 + n4 * 2];
            float4 TB = t14[j * 65 + n4 * 2 + 1];
            float4 PA = pc4[i * 64 + n4 * 2];
            float4 PB = pc4[i * 64 + n4 * 2 + 1];
            accre += PA.x * TA.x - PA.y * TA.y;
            accim += PA.x * TA.y + PA.y * TA.x;
            accre += PA.z * TA.z - PA.w * TA.w;
            accim += PA.z * TA.w + PA.w * TA.z;
            accre += PB.x * TB.x - PB.y * TB.y;
            accim += PB.x * TB.y + PB.y * TB.x;
            accre += PB.z * TB.z - PB.w * TB.w;
            accim += PB.z * TB.w + PB.w * TB.z;
        }
        Xb[(size_t)bc * 448 + p] = make_float2(accre * NORM, accim * NORM);
    }
}

// ---------------------------------------------------------------- channel mix (per mode)
// reads X[bc][448] (gather, L3-resident), writes OK[ij][bo] coalesced
__launch_bounds__(256, 2)
__global__ void k_mix(const float2* __restrict__ Xg, const float2* __restrict__ Rt,
                      float2* __restrict__ OK) {
    __shared__ float2 Xs[2048];
    __shared__ float2 Rs[4096];
    int t = threadIdx.x;
    int ij = blockIdx.x;
    for (int k = t; k < 2048; k += 256) Xs[k] = Xg[(size_t)k * 448 + ij];
    for (int k = t; k < 4096; k += 256) Rs[k] = Rt[(size_t)ij * 4096 + k];
    __syncthreads();
    int o = t & 63, bg = t >> 6;
    float accre[8], accim[8];
    #pragma unroll
    for (int i = 0; i < 8; ++i) { accre[i] = 0.f; accim[i] = 0.f; }
    for (int c = 0; c < 64; ++c) {
        float2 rv = Rs[c * 64 + o];
        #pragma unroll
        for (int bb = 0; bb < 8; ++bb) {
            float2 xv = Xs[(bg * 8 + bb) * 64 + c];
            accre[bb] += xv.x * rv.x - xv.y * rv.y;
            accim[bb] += xv.x * rv.y + xv.y * rv.x;
        }
    }
    #pragma unroll
    for (int bb = 0; bb < 8; ++bb)
        OK[(size_t)ij * 2048 + (bg * 8 + bb) * 64 + o] = make_float2(accre[bb], accim[bb]);
}

// ---------------------------------------------------------------- inverse DFT (per b,o)
__launch_bounds__(256, 2)
__global__ void k_inv(const float2* __restrict__ OKg, const float2* __restrict__ qx,
                      const float2* __restrict__ qt, float* __restrict__ out) {
    __shared__ __align__(16) float2 qs[21 * 128];
    __shared__ __align__(16) float2 t2s[128 * 22];
    __shared__ float2 oks[441];
    const int t = threadIdx.x;
    const int bo = blockIdx.x;

    for (int k = t; k < 441; k += 256) oks[k] = OKg[(size_t)k * 2048 + bo];
    {
        const float4* g4 = reinterpret_cast<const float4*>(qx);
        float4* s4 = reinterpret_cast<float4*>(qs);
        for (int k = t; k < 1344; k += 256) s4[k] = g4[k];
    }
    __syncthreads();
    // phase A: T2[n][j] = sum_i ok[i][j] * qx[i][n]
    {
        const int ng = t & 31, jg = t >> 5;
        const int jbase = (jg < 5) ? 3 * jg : 15 + 2 * (jg - 5);
        const int jcnt  = (jg < 5) ? 3 : 2;
        float are[4][3], aim[4][3];
        #pragma unroll
        for (int r = 0; r < 4; ++r)
            #pragma unroll
            for (int jj = 0; jj < 3; ++jj) { are[r][jj] = 0.f; aim[r][jj] = 0.f; }
        const float4* qs4 = reinterpret_cast<const float4*>(qs);
        for (int i = 0; i < 21; ++i) {
            float4 QA = qs4[i * 64 + ng * 2];
            float4 QB = qs4[i * 64 + ng * 2 + 1];
            #pragma unroll
            for (int jj = 0; jj < 3; ++jj) {
                if (jj < jcnt) {
                    float2 okv = oks[i * 21 + jbase + jj];
                    are[0][jj] += okv.x * QA.x - okv.y * QA.y;
                    aim[0][jj] += okv.x * QA.y + okv.y * QA.x;
                    are[1][jj] += okv.x * QA.z - okv.y * QA.w;
                    aim[1][jj] += okv.x * QA.w + okv.y * QA.z;
                    are[2][jj] += okv.x * QB.x - okv.y * QB.y;
                    aim[2][jj] += okv.x * QB.y + okv.y * QB.x;
                    are[3][jj] += okv.x * QB.z - okv.y * QB.w;
                    aim[3][jj] += okv.x * QB.w + okv.y * QB.z;
                }
            }
        }
        #pragma unroll
        for (int jj = 0; jj < 3; ++jj) {
            if (jj < jcnt) {
                #pragma unroll
                for (int r = 0; r < 4; ++r)
                    t2s[(ng * 4 + r) * 22 + jbase + jj] = make_float2(are[r][jj], aim[r][jj]);
            }
        }
    }
    __syncthreads();
    {   // reload twiddle with qt
        const float4* g4 = reinterpret_cast<const float4*>(qt);
        float4* s4 = reinterpret_cast<float4*>(qs);
        for (int k = t; k < 1344; k += 256) s4[k] = g4[k];
    }
    __syncthreads();
    // phase B: out[n][m] = Re( sum_j T2[n][j] * qt[j][m] )
    {
        const int mg = t & 31, ng = t >> 5;
        const float4* qs4 = reinterpret_cast<const float4*>(qs);
        float* og = out + (size_t)bo * 16384;
        for (int nb = 0; nb < 4; ++nb) {
            int n0 = nb * 32 + ng * 4;
            float acc[4][4];
            #pragma unroll
            for (int r = 0; r < 4; ++r)
                #pragma unroll
                for (int m = 0; m < 4; ++m) acc[r][m] = 0.f;
            for (int j = 0; j < 21; ++j) {
                float4 QA = qs4[j * 64 + mg * 2];
                float4 QB = qs4[j * 64 + mg * 2 + 1];
                #pragma unroll
                for (int r = 0; r < 4; ++r) {
                    float2 t2v = t2s[(n0 + r) * 22 + j];
                    acc[r][0] += t2v.x * QA.x - t2v.y * QA.y;
                    acc[r][1] += t2v.x * QA.z - t2v.y * QA.w;
                    acc[r][2] += t2v.x * QB.x - t2v.y * QB.y;
                    acc[r][3] += t2v.x * QB.z - t2v.y * QB.w;
                }
            }
            #pragma unroll
            for (int r = 0; r < 4; ++r) {
                float4 v = make_float4(acc[r][0] * NORM, acc[r][1] * NORM,
                                       acc[r][2] * NORM, acc[r][3] * NORM);
                *reinterpret_cast<float4*>(og + (n0 + r) * 128 + mg * 4) = v;
            }
        }
    }
}

// ---------------------------------------------------------------- launch
extern "C" void kernel_launch(void* const* d_in, const int* in_sizes, int n_in,
                              void* d_out, int out_size, void* d_ws, size_t ws_size,
                              hipStream_t stream) {
    const float* x   = (const float*)d_in[0];
    const float* wr  = (const float*)d_in[1];
    const float* wi  = (const float*)d_in[2];
    const float* thx = (const float*)d_in[3];
    const float* tht = (const float*)d_in[4];
    float* out = (float*)d_out;

    char* ws = (char*)d_ws;
    float2* pc = (float2*)(ws);
    float2* qx = (float2*)(ws + 21504);
    float2* qt = (float2*)(ws + 43008);
    float2* Rt = (float2*)(ws + 64512);                          // [441][4096] float2 = 14450688 B
    float2* Xb = (float2*)(ws + 64512 + 14450688);               // [2048][448] float2 = 7340032 B
    float2* OK = (float2*)(ws + 64512 + 14450688 + 7340032);     // [441][2048] float2 = 7225344 B

    k_tables<<<1, 256, 0, stream>>>(thx, tht, pc, qx, qt);
    k_wt<<<dim3(7, 64), 256, 0, stream>>>(wr, wi, Rt);
    k_fwd<<<2048, 256, 0, stream>>>(x, pc, Xb);
    k_mix<<<441, 256, 0, stream>>>(Xb, Rt, OK);
    k_inv<<<2048, 256, 0, stream>>>(OK, qx, qt, out);
}

// Round 4
// 273.241 us; speedup vs baseline: 3.0231x; 2.9603x over previous
//
#include <hip/hip_runtime.h>
#include <math.h>

#define TWO_PI 6.28318530717958647692f
#define PI_F   3.14159265358979323846f
#define NORM   0.0078125f  /* 1/sqrt(128*128) */

// ---------------------------------------------------------------- tables
// PT[n][i] = exp(-2pi*i_img * k_i * n / 128)   (layout [128][21] float2)
// qx[i][n], qt[j][m] : inverse complex-frequency twiddles ([21][128] float2)
__device__ __forceinline__ float kfreq(int i) { return (i <= 10) ? (float)i : (float)(i - 21); }

__global__ void k_tables(const float* __restrict__ thrx, const float* __restrict__ thrt,
                         float2* __restrict__ PT, float2* __restrict__ qx, float2* __restrict__ qt) {
    int t = threadIdx.x;
    for (int idx = t; idx < 21 * 128; idx += 256) {
        int i = idx >> 7, n = idx & 127;
        float k = kfreq(i), fn = (float)n;
        float s, c;
        float ang = -TWO_PI * k * fn * (1.0f / 128.0f);
        sincosf(ang, &s, &c);
        PT[n * 21 + i] = make_float2(c, s);   // transposed store
        {
            float raw = thrx[i];
            float sig = 1.0f / (1.0f + expf(-raw));
            float th = (k < 0.0f) ? (0.5f * PI_F) * (1.0f + sig) : PI_F * sig;
            float ka = fabsf(k);
            float amp = expf(-TWO_PI * ka * sinf(th) * fn * (1.0f / 128.0f));
            float a2 = TWO_PI * ka * cosf(th) * fn * (1.0f / 128.0f);
            sincosf(a2, &s, &c);
            qx[idx] = make_float2(amp * c, amp * s);
        }
        {
            float raw = thrt[i];
            float sig = 1.0f / (1.0f + expf(-raw));
            float th = (k < 0.0f) ? (0.5f * PI_F) * (1.0f + sig) : PI_F * sig;
            float ka = fabsf(k);
            float amp = expf(-TWO_PI * ka * sinf(th) * fn * (1.0f / 128.0f));
            float a2 = TWO_PI * ka * cosf(th) * fn * (1.0f / 128.0f);
            sincosf(a2, &s, &c);
            qt[idx] = make_float2(amp * c, amp * s);
        }
    }
}

// ---------------------------------------------------------------- weight transpose [co][ij] -> [ij][co]
__global__ void k_wt(const float* __restrict__ wr, const float* __restrict__ wi,
                     float2* __restrict__ Rt) {
    __shared__ float2 tile[64][65];
    const int tx = threadIdx.x & 63;
    const int ty = threadIdx.x >> 6;
    const int ij0 = blockIdx.x * 64;
    const int co0 = blockIdx.y * 64;
    #pragma unroll
    for (int r = 0; r < 16; ++r) {
        int row = ty + r * 4;
        int col = ij0 + tx;
        if (col < 441) {
            size_t g = (size_t)(co0 + row) * 441 + col;
            tile[row][tx] = make_float2(wr[g], wi[g]);
        }
    }
    __syncthreads();
    #pragma unroll
    for (int r = 0; r < 16; ++r) {
        int row = ty + r * 4;
        int ij = ij0 + row;
        if (ij < 441)
            Rt[(size_t)ij * 4096 + co0 + tx] = tile[tx][row];
    }
}

// ---------------------------------------------------------------- forward DFT (per b,c)
// phase1: T1[n][j] = sum_m x[n][m] PT[m][j], j=0..10 (conj symmetry; x real)
// phase2: X[i][j]  = sum_n PT[n][i] T1[n][j], i=0..20, j=0..10; conj-fill to 441
__launch_bounds__(256, 4)
__global__ void k_fwd(const float* __restrict__ x, const float2* __restrict__ PT,
                      float2* __restrict__ Xb) {
    __shared__ __align__(16) char ubuf[21504];      // union: xsT [32][130] f32 / pxT [128][21] f2
    __shared__ __align__(16) float2 t1s[128 * 11];
    __shared__ float2 xout[231];
    float*  xsT = reinterpret_cast<float*>(ubuf);
    float2* pxT = reinterpret_cast<float2*>(ubuf);
    const int t = threadIdx.x;
    const int bc = blockIdx.x;
    const int lane = t & 63;
    const int w = t >> 6;
    const int rh = w & 1;
    const int jh = w >> 1;                                      // wave-uniform
    const int jbase = __builtin_amdgcn_readfirstlane(jh * 5);   // j = jbase..jbase+5 (overlap at 5 benign)
    const int n = lane + 64 * rh;

    float tre[6], tim[6];
    #pragma unroll
    for (int jj = 0; jj < 6; ++jj) { tre[jj] = 0.f; tim[jj] = 0.f; }

    const float* xg = x + (size_t)bc * 16384;
    for (int ch = 0; ch < 4; ++ch) {
        __syncthreads();
        #pragma unroll
        for (int pass = 0; pass < 4; ++pass) {      // stage 128 rows x 32 cols, transposed
            int fid = pass * 256 + t;
            int row = fid >> 3, f = fid & 7;
            float4 v = *reinterpret_cast<const float4*>(xg + row * 128 + ch * 32 + f * 4);
            xsT[(f * 4 + 0) * 130 + row] = v.x;
            xsT[(f * 4 + 1) * 130 + row] = v.y;
            xsT[(f * 4 + 2) * 130 + row] = v.z;
            xsT[(f * 4 + 3) * 130 + row] = v.w;
        }
        __syncthreads();
        for (int mm = 0; mm < 32; ++mm) {
            int m = ch * 32 + mm;
            const float2* pw = PT + m * 21 + jbase;             // wave-uniform address
            float2 w0 = pw[0], w1 = pw[1], w2 = pw[2], w3 = pw[3], w4 = pw[4], w5 = pw[5];
            float xv = xsT[mm * 130 + n];                       // stride-1 per lane, conflict-free
            tre[0] += xv * w0.x; tim[0] += xv * w0.y;
            tre[1] += xv * w1.x; tim[1] += xv * w1.y;
            tre[2] += xv * w2.x; tim[2] += xv * w2.y;
            tre[3] += xv * w3.x; tim[3] += xv * w3.y;
            tre[4] += xv * w4.x; tim[4] += xv * w4.y;
            tre[5] += xv * w5.x; tim[5] += xv * w5.y;
        }
    }
    #pragma unroll
    for (int jj = 0; jj < 6; ++jj)
        t1s[n * 11 + jbase + jj] = make_float2(tre[jj], tim[jj]);
    __syncthreads();
    {   // stage pxT = PT into LDS (overlays xsT) -- FULL table: 1344 float4
        const float4* g4 = reinterpret_cast<const float4*>(PT);
        float4* s4 = reinterpret_cast<float4*>(pxT);
        for (int k = t; k < 1344; k += 256) s4[k] = g4[k];
    }
    __syncthreads();
    if (t < 231) {
        int i = t / 11, j = t % 11;
        float are = 0.f, aim = 0.f;
        for (int nn = 0; nn < 128; ++nn) {
            float2 pv = pxT[nn * 21 + i];
            float2 tv = t1s[nn * 11 + j];
            are += pv.x * tv.x - pv.y * tv.y;
            aim += pv.x * tv.y + pv.y * tv.x;
        }
        xout[i * 11 + j] = make_float2(are * NORM, aim * NORM);
    }
    __syncthreads();
    for (int p = t; p < 441; p += 256) {
        int i = p / 21, j = p % 21;
        float2 v;
        if (j < 11) v = xout[i * 11 + j];
        else {
            float2 u = xout[((21 - i) % 21) * 11 + (21 - j)];
            v = make_float2(u.x, -u.y);
        }
        Xb[(size_t)bc * 448 + p] = v;
    }
}

// ---------------------------------------------------------------- channel mix (per mode)
__launch_bounds__(256, 2)
__global__ void k_mix(const float2* __restrict__ Xg, const float2* __restrict__ Rt,
                      float2* __restrict__ OK) {
    __shared__ float2 Xs[2048];
    __shared__ float2 Rs[4096];
    int t = threadIdx.x;
    int ij = blockIdx.x;
    for (int k = t; k < 2048; k += 256) Xs[k] = Xg[(size_t)k * 448 + ij];
    for (int k = t; k < 4096; k += 256) Rs[k] = Rt[(size_t)ij * 4096 + k];
    __syncthreads();
    int o = t & 63, bg = t >> 6;
    float accre[8], accim[8];
    #pragma unroll
    for (int i = 0; i < 8; ++i) { accre[i] = 0.f; accim[i] = 0.f; }
    for (int c = 0; c < 64; ++c) {
        float2 rv = Rs[c * 64 + o];
        #pragma unroll
        for (int bb = 0; bb < 8; ++bb) {
            float2 xv = Xs[(bg * 8 + bb) * 64 + c];
            accre[bb] += xv.x * rv.x - xv.y * rv.y;
            accim[bb] += xv.x * rv.y + xv.y * rv.x;
        }
    }
    #pragma unroll
    for (int bb = 0; bb < 8; ++bb)
        OK[(size_t)ij * 2048 + (bg * 8 + bb) * 64 + o] = make_float2(accre[bb], accim[bb]);
}

// ---------------------------------------------------------------- inverse DFT (per b,o)
// phase A: T2[n][j] = sum_i ok[i][j] qx[i][n]; phase B: out[n][m] = Re sum_j T2[n][j] qt[j][m]
__launch_bounds__(256, 3)
__global__ void k_inv(const float2* __restrict__ OKg, const float2* __restrict__ qx,
                      const float2* __restrict__ qt, float* __restrict__ out) {
    __shared__ __align__(16) float2 qs[21 * 130];   // padded rows
    __shared__ __align__(16) float2 t2s[128 * 22];
    __shared__ float2 oks[441];
    const int t = threadIdx.x;
    const int bo = blockIdx.x;

    for (int k = t; k < 441; k += 256) oks[k] = OKg[(size_t)k * 2048 + bo];
    for (int k = t; k < 1344; k += 256) {           // qs[i][130] <- qx[i][128] row-padded
        int row = k >> 6, c4 = k & 63;
        reinterpret_cast<float4*>(qs + row * 130)[c4] =
            reinterpret_cast<const float4*>(qx + row * 128)[c4];
    }
    __syncthreads();
    // phase A: rows n = ng + 32r
    {
        const int ng = t & 31, jg = t >> 5;
        const int jbase = (jg < 5) ? 3 * jg : 15 + 2 * (jg - 5);
        const int jcnt  = (jg < 5) ? 3 : 2;
        float are[4][3], aim[4][3];
        #pragma unroll
        for (int r = 0; r < 4; ++r)
            #pragma unroll
            for (int jj = 0; jj < 3; ++jj) { are[r][jj] = 0.f; aim[r][jj] = 0.f; }
        for (int i = 0; i < 21; ++i) {
            float2 q0 = qs[i * 130 + ng];
            float2 q1 = qs[i * 130 + ng + 32];
            float2 q2 = qs[i * 130 + ng + 64];
            float2 q3 = qs[i * 130 + ng + 96];
            #pragma unroll
            for (int jj = 0; jj < 3; ++jj) {
                if (jj < jcnt) {
                    float2 okv = oks[i * 21 + jbase + jj];
                    are[0][jj] += okv.x * q0.x - okv.y * q0.y;
                    aim[0][jj] += okv.x * q0.y + okv.y * q0.x;
                    are[1][jj] += okv.x * q1.x - okv.y * q1.y;
                    aim[1][jj] += okv.x * q1.y + okv.y * q1.x;
                    are[2][jj] += okv.x * q2.x - okv.y * q2.y;
                    aim[2][jj] += okv.x * q2.y + okv.y * q2.x;
                    are[3][jj] += okv.x * q3.x - okv.y * q3.y;
                    aim[3][jj] += okv.x * q3.y + okv.y * q3.x;
                }
            }
        }
        #pragma unroll
        for (int jj = 0; jj < 3; ++jj) {
            if (jj < jcnt) {
                #pragma unroll
                for (int r = 0; r < 4; ++r)
                    t2s[(ng + 32 * r) * 22 + jbase + jj] = make_float2(are[r][jj], aim[r][jj]);
            }
        }
    }
    __syncthreads();
    // phase B: per-wave m-tile of 16, qt via wave-uniform loads, t2 per-lane LDS
    {
        const int lane = t & 63, w = t >> 6;
        float* og = out + (size_t)bo * 16384;
        for (int half = 0; half < 2; ++half) {
            const int m0 = __builtin_amdgcn_readfirstlane(w * 32 + half * 16);
            float accA[16], accB[16];
            #pragma unroll
            for (int mm = 0; mm < 16; ++mm) { accA[mm] = 0.f; accB[mm] = 0.f; }
            for (int j = 0; j < 21; ++j) {
                const float2* qw = qt + j * 128 + m0;       // wave-uniform address
                float2 t0 = t2s[lane * 22 + j];
                float2 t1v = t2s[(lane + 64) * 22 + j];
                #pragma unroll
                for (int mm = 0; mm < 16; ++mm) {
                    float2 qv = qw[mm];
                    accA[mm] += t0.x * qv.x - t0.y * qv.y;
                    accB[mm] += t1v.x * qv.x - t1v.y * qv.y;
                }
            }
            #pragma unroll
            for (int q = 0; q < 4; ++q) {
                float4 vA = make_float4(accA[q*4+0]*NORM, accA[q*4+1]*NORM, accA[q*4+2]*NORM, accA[q*4+3]*NORM);
                float4 vB = make_float4(accB[q*4+0]*NORM, accB[q*4+1]*NORM, accB[q*4+2]*NORM, accB[q*4+3]*NORM);
                *reinterpret_cast<float4*>(og + lane * 128 + m0 + q * 4) = vA;
                *reinterpret_cast<float4*>(og + (lane + 64) * 128 + m0 + q * 4) = vB;
            }
        }
    }
}

// ---------------------------------------------------------------- launch
extern "C" void kernel_launch(void* const* d_in, const int* in_sizes, int n_in,
                              void* d_out, int out_size, void* d_ws, size_t ws_size,
                              hipStream_t stream) {
    const float* x   = (const float*)d_in[0];
    const float* wr  = (const float*)d_in[1];
    const float* wi  = (const float*)d_in[2];
    const float* thx = (const float*)d_in[3];
    const float* tht = (const float*)d_in[4];
    float* out = (float*)d_out;

    char* ws = (char*)d_ws;
    float2* PT = (float2*)(ws);                                   // 21504 B
    float2* qx = (float2*)(ws + 21504);                           // 21504 B
    float2* qt = (float2*)(ws + 43008);                           // 21504 B
    float2* Rt = (float2*)(ws + 64512);                           // 14450688 B
    float2* Xb = (float2*)(ws + 64512 + 14450688);                // [2048][448] f2 = 7340032 B
    float2* OK = (float2*)(ws + 64512 + 14450688 + 7340032);      // [441][2048] f2 = 7225344 B

    k_tables<<<1, 256, 0, stream>>>(thx, tht, PT, qx, qt);
    k_wt<<<dim3(7, 64), 256, 0, stream>>>(wr, wi, Rt);
    k_fwd<<<2048, 256, 0, stream>>>(x, PT, Xb);
    k_mix<<<441, 256, 0, stream>>>(Xb, Rt, OK);
    k_inv<<<2048, 256, 0, stream>>>(OK, qx, qt, out);
}

// Round 5
// 218.772 us; speedup vs baseline: 3.7758x; 1.2490x over previous
//
#include <hip/hip_runtime.h>
#include <math.h>

#define TWO_PI 6.28318530717958647692f
#define PI_F   3.14159265358979323846f
#define NORM   0.0078125f  /* 1/sqrt(128*128) */

// ---------------------------------------------------------------- tables
// PT[n][i] = exp(-2pi*i_img * k_i * n / 128)   (layout [128][21] float2)
// qx[i][n], qt[j][m] : inverse complex-frequency twiddles ([21][128] float2)
__device__ __forceinline__ float kfreq(int i) { return (i <= 10) ? (float)i : (float)(i - 21); }

__global__ void k_tables(const float* __restrict__ thrx, const float* __restrict__ thrt,
                         float2* __restrict__ PT, float2* __restrict__ qx, float2* __restrict__ qt) {
    int t = threadIdx.x;
    for (int idx = t; idx < 21 * 128; idx += 256) {
        int i = idx >> 7, n = idx & 127;
        float k = kfreq(i), fn = (float)n;
        float s, c;
        float ang = -TWO_PI * k * fn * (1.0f / 128.0f);
        sincosf(ang, &s, &c);
        PT[n * 21 + i] = make_float2(c, s);   // transposed store
        {
            float raw = thrx[i];
            float sig = 1.0f / (1.0f + expf(-raw));
            float th = (k < 0.0f) ? (0.5f * PI_F) * (1.0f + sig) : PI_F * sig;
            float ka = fabsf(k);
            float amp = expf(-TWO_PI * ka * sinf(th) * fn * (1.0f / 128.0f));
            float a2 = TWO_PI * ka * cosf(th) * fn * (1.0f / 128.0f);
            sincosf(a2, &s, &c);
            qx[idx] = make_float2(amp * c, amp * s);
        }
        {
            float raw = thrt[i];
            float sig = 1.0f / (1.0f + expf(-raw));
            float th = (k < 0.0f) ? (0.5f * PI_F) * (1.0f + sig) : PI_F * sig;
            float ka = fabsf(k);
            float amp = expf(-TWO_PI * ka * sinf(th) * fn * (1.0f / 128.0f));
            float a2 = TWO_PI * ka * cosf(th) * fn * (1.0f / 128.0f);
            sincosf(a2, &s, &c);
            qt[idx] = make_float2(amp * c, amp * s);
        }
    }
}

// ---------------------------------------------------------------- weight transpose [co][ij] -> [ij][co]
__global__ void k_wt(const float* __restrict__ wr, const float* __restrict__ wi,
                     float2* __restrict__ Rt) {
    __shared__ float2 tile[64][65];
    const int tx = threadIdx.x & 63;
    const int ty = threadIdx.x >> 6;
    const int ij0 = blockIdx.x * 64;
    const int co0 = blockIdx.y * 64;
    #pragma unroll
    for (int r = 0; r < 16; ++r) {
        int row = ty + r * 4;
        int col = ij0 + tx;
        if (col < 441) {
            size_t g = (size_t)(co0 + row) * 441 + col;
            tile[row][tx] = make_float2(wr[g], wi[g]);
        }
    }
    __syncthreads();
    #pragma unroll
    for (int r = 0; r < 16; ++r) {
        int row = ty + r * 4;
        int ij = ij0 + row;
        if (ij < 441)
            Rt[(size_t)ij * 4096 + co0 + tx] = tile[tx][row];
    }
}

// ---------------------------------------------------------------- forward DFT (per b,c)  [unchanged]
__launch_bounds__(256, 4)
__global__ void k_fwd(const float* __restrict__ x, const float2* __restrict__ PT,
                      float2* __restrict__ Xb) {
    __shared__ __align__(16) char ubuf[21504];      // union: xsT [32][130] f32 / pxT [128][21] f2
    __shared__ __align__(16) float2 t1s[128 * 11];
    __shared__ float2 xout[231];
    float*  xsT = reinterpret_cast<float*>(ubuf);
    float2* pxT = reinterpret_cast<float2*>(ubuf);
    const int t = threadIdx.x;
    const int bc = blockIdx.x;
    const int lane = t & 63;
    const int w = t >> 6;
    const int rh = w & 1;
    const int jh = w >> 1;
    const int jbase = __builtin_amdgcn_readfirstlane(jh * 5);
    const int n = lane + 64 * rh;

    float tre[6], tim[6];
    #pragma unroll
    for (int jj = 0; jj < 6; ++jj) { tre[jj] = 0.f; tim[jj] = 0.f; }

    const float* xg = x + (size_t)bc * 16384;
    for (int ch = 0; ch < 4; ++ch) {
        __syncthreads();
        #pragma unroll
        for (int pass = 0; pass < 4; ++pass) {
            int fid = pass * 256 + t;
            int row = fid >> 3, f = fid & 7;
            float4 v = *reinterpret_cast<const float4*>(xg + row * 128 + ch * 32 + f * 4);
            xsT[(f * 4 + 0) * 130 + row] = v.x;
            xsT[(f * 4 + 1) * 130 + row] = v.y;
            xsT[(f * 4 + 2) * 130 + row] = v.z;
            xsT[(f * 4 + 3) * 130 + row] = v.w;
        }
        __syncthreads();
        for (int mm = 0; mm < 32; ++mm) {
            int m = ch * 32 + mm;
            const float2* pw = PT + m * 21 + jbase;
            float2 w0 = pw[0], w1 = pw[1], w2 = pw[2], w3 = pw[3], w4 = pw[4], w5 = pw[5];
            float xv = xsT[mm * 130 + n];
            tre[0] += xv * w0.x; tim[0] += xv * w0.y;
            tre[1] += xv * w1.x; tim[1] += xv * w1.y;
            tre[2] += xv * w2.x; tim[2] += xv * w2.y;
            tre[3] += xv * w3.x; tim[3] += xv * w3.y;
            tre[4] += xv * w4.x; tim[4] += xv * w4.y;
            tre[5] += xv * w5.x; tim[5] += xv * w5.y;
        }
    }
    #pragma unroll
    for (int jj = 0; jj < 6; ++jj)
        t1s[n * 11 + jbase + jj] = make_float2(tre[jj], tim[jj]);
    __syncthreads();
    {   // stage pxT = PT into LDS (overlays xsT) -- FULL table: 1344 float4
        const float4* g4 = reinterpret_cast<const float4*>(PT);
        float4* s4 = reinterpret_cast<float4*>(pxT);
        for (int k = t; k < 1344; k += 256) s4[k] = g4[k];
    }
    __syncthreads();
    if (t < 231) {
        int i = t / 11, j = t % 11;
        float are = 0.f, aim = 0.f;
        for (int nn = 0; nn < 128; ++nn) {
            float2 pv = pxT[nn * 21 + i];
            float2 tv = t1s[nn * 11 + j];
            are += pv.x * tv.x - pv.y * tv.y;
            aim += pv.x * tv.y + pv.y * tv.x;
        }
        xout[i * 11 + j] = make_float2(are * NORM, aim * NORM);
    }
    __syncthreads();
    for (int p = t; p < 441; p += 256) {
        int i = p / 21, j = p % 21;
        float2 v;
        if (j < 11) v = xout[i * 11 + j];
        else {
            float2 u = xout[((21 - i) % 21) * 11 + (21 - j)];
            v = make_float2(u.x, -u.y);
        }
        Xb[(size_t)bc * 448 + p] = v;
    }
}

// ---------------------------------------------------------------- channel mix (per mode) [unchanged]
__launch_bounds__(256, 2)
__global__ void k_mix(const float2* __restrict__ Xg, const float2* __restrict__ Rt,
                      float2* __restrict__ OK) {
    __shared__ float2 Xs[2048];
    __shared__ float2 Rs[4096];
    int t = threadIdx.x;
    int ij = blockIdx.x;
    for (int k = t; k < 2048; k += 256) Xs[k] = Xg[(size_t)k * 448 + ij];
    for (int k = t; k < 4096; k += 256) Rs[k] = Rt[(size_t)ij * 4096 + k];
    __syncthreads();
    int o = t & 63, bg = t >> 6;
    float accre[8], accim[8];
    #pragma unroll
    for (int i = 0; i < 8; ++i) { accre[i] = 0.f; accim[i] = 0.f; }
    for (int c = 0; c < 64; ++c) {
        float2 rv = Rs[c * 64 + o];
        #pragma unroll
        for (int bb = 0; bb < 8; ++bb) {
            float2 xv = Xs[(bg * 8 + bb) * 64 + c];
            accre[bb] += xv.x * rv.x - xv.y * rv.y;
            accim[bb] += xv.x * rv.y + xv.y * rv.x;
        }
    }
    #pragma unroll
    for (int bb = 0; bb < 8; ++bb)
        OK[(size_t)ij * 2048 + (bg * 8 + bb) * 64 + o] = make_float2(accre[bb], accim[bb]);
}

// ---------------------------------------------------------------- inverse DFT (per b,o)
// phase A: T2[j][n] = sum_i ok[i][j] qx[i][n]   (t2s transposed: [j][130])
// phase B: out[n][m] = Re sum_j T2[j][n] qt[j][m]  -- all LDS, conflict-free
__launch_bounds__(256, 3)
__global__ void k_inv(const float2* __restrict__ OKg, const float2* __restrict__ qx,
                      const float2* __restrict__ qt, float* __restrict__ out) {
    __shared__ __align__(16) float2 qs[21 * 130];   // phase A: qx rows; phase B: qt rows (reused)
    __shared__ __align__(16) float2 t2s[21 * 130];  // t2s[j][n], row-padded
    __shared__ float2 oks[441];
    const int t = threadIdx.x;
    const int bo = blockIdx.x;

    for (int k = t; k < 441; k += 256) oks[k] = OKg[(size_t)k * 2048 + bo];
    for (int k = t; k < 1344; k += 256) {           // qs[i][130] <- qx[i][128]
        int row = k >> 6, c4 = k & 63;
        reinterpret_cast<float4*>(qs + row * 130)[c4] =
            reinterpret_cast<const float4*>(qx + row * 128)[c4];
    }
    __syncthreads();
    // phase A: rows n = ng + 32r, write t2s[j][n]
    {
        const int ng = t & 31, jg = t >> 5;
        const int jbase = (jg < 5) ? 3 * jg : 15 + 2 * (jg - 5);
        const int jcnt  = (jg < 5) ? 3 : 2;
        float are[4][3], aim[4][3];
        #pragma unroll
        for (int r = 0; r < 4; ++r)
            #pragma unroll
            for (int jj = 0; jj < 3; ++jj) { are[r][jj] = 0.f; aim[r][jj] = 0.f; }
        for (int i = 0; i < 21; ++i) {
            float2 q0 = qs[i * 130 + ng];
            float2 q1 = qs[i * 130 + ng + 32];
            float2 q2 = qs[i * 130 + ng + 64];
            float2 q3 = qs[i * 130 + ng + 96];
            #pragma unroll
            for (int jj = 0; jj < 3; ++jj) {
                if (jj < jcnt) {
                    float2 okv = oks[i * 21 + jbase + jj];
                    are[0][jj] += okv.x * q0.x - okv.y * q0.y;
                    aim[0][jj] += okv.x * q0.y + okv.y * q0.x;
                    are[1][jj] += okv.x * q1.x - okv.y * q1.y;
                    aim[1][jj] += okv.x * q1.y + okv.y * q1.x;
                    are[2][jj] += okv.x * q2.x - okv.y * q2.y;
                    aim[2][jj] += okv.x * q2.y + okv.y * q2.x;
                    are[3][jj] += okv.x * q3.x - okv.y * q3.y;
                    aim[3][jj] += okv.x * q3.y + okv.y * q3.x;
                }
            }
        }
        #pragma unroll
        for (int jj = 0; jj < 3; ++jj) {
            if (jj < jcnt) {
                #pragma unroll
                for (int r = 0; r < 4; ++r)
                    t2s[(jbase + jj) * 130 + ng + 32 * r] = make_float2(are[r][jj], aim[r][jj]);
            }
        }
    }
    __syncthreads();     // phase A done (qs reads finished) -> safe to restage
    for (int k = t; k < 1344; k += 256) {           // qs[j][130] <- qt[j][128]
        int row = k >> 6, c4 = k & 63;
        reinterpret_cast<float4*>(qs + row * 130)[c4] =
            reinterpret_cast<const float4*>(qt + row * 128)[c4];
    }
    __syncthreads();
    // phase B: all-LDS. lane owns m = ml+32q (q=0..3), rows nbase..nbase+15.
    {
        const int lane = t & 63, w = t >> 6;
        const int ml = lane & 31;
        const int nh = lane >> 5;
        const int nbase = w * 32 + nh * 16;
        float acc[16][4];
        #pragma unroll
        for (int r = 0; r < 16; ++r)
            #pragma unroll
            for (int q = 0; q < 4; ++q) acc[r][q] = 0.f;
        for (int j = 0; j < 21; ++j) {
            float2 q0 = qs[j * 130 + ml];
            float2 q1 = qs[j * 130 + ml + 32];
            float2 q2 = qs[j * 130 + ml + 64];
            float2 q3 = qs[j * 130 + ml + 96];
            #pragma unroll
            for (int r = 0; r < 16; ++r) {
                float2 tv = t2s[j * 130 + nbase + r];   // half-wave broadcast
                acc[r][0] += tv.x * q0.x - tv.y * q0.y;
                acc[r][1] += tv.x * q1.x - tv.y * q1.y;
                acc[r][2] += tv.x * q2.x - tv.y * q2.y;
                acc[r][3] += tv.x * q3.x - tv.y * q3.y;
            }
        }
        float* og = out + (size_t)bo * 16384;
        #pragma unroll
        for (int r = 0; r < 16; ++r) {
            #pragma unroll
            for (int q = 0; q < 4; ++q)
                og[(nbase + r) * 128 + ml + 32 * q] = acc[r][q] * NORM;
        }
    }
}

// ---------------------------------------------------------------- launch
extern "C" void kernel_launch(void* const* d_in, const int* in_sizes, int n_in,
                              void* d_out, int out_size, void* d_ws, size_t ws_size,
                              hipStream_t stream) {
    const float* x   = (const float*)d_in[0];
    const float* wr  = (const float*)d_in[1];
    const float* wi  = (const float*)d_in[2];
    const float* thx = (const float*)d_in[3];
    const float* tht = (const float*)d_in[4];
    float* out = (float*)d_out;

    char* ws = (char*)d_ws;
    float2* PT = (float2*)(ws);                                   // 21504 B
    float2* qx = (float2*)(ws + 21504);                           // 21504 B
    float2* qt = (float2*)(ws + 43008);                           // 21504 B
    float2* Rt = (float2*)(ws + 64512);                           // 14450688 B
    float2* Xb = (float2*)(ws + 64512 + 14450688);                // [2048][448] f2 = 7340032 B
    float2* OK = (float2*)(ws + 64512 + 14450688 + 7340032);      // [441][2048] f2 = 7225344 B

    k_tables<<<1, 256, 0, stream>>>(thx, tht, PT, qx, qt);
    k_wt<<<dim3(7, 64), 256, 0, stream>>>(wr, wi, Rt);
    k_fwd<<<2048, 256, 0, stream>>>(x, PT, Xb);
    k_mix<<<441, 256, 0, stream>>>(Xb, Rt, OK);
    k_inv<<<2048, 256, 0, stream>>>(OK, qx, qt, out);
}

// Round 6
// 179.761 us; speedup vs baseline: 4.5952x; 1.2170x over previous
//
#include <hip/hip_runtime.h>
#include <math.h>

#define TWO_PI 6.28318530717958647692f
#define PI_F   3.14159265358979323846f
#define NORM   0.0078125f  /* 1/sqrt(128*128) */

// ---------------------------------------------------------------- tables
// W1[l] = exp(-2pi*i_img * l / 128)  (128 entries; fwd twiddles = W1[(k*n)&127])
// qx[i][n], qt[j][m] : inverse complex-frequency twiddles ([21][128] float2)
__device__ __forceinline__ float kfreq(int i) { return (i <= 10) ? (float)i : (float)(i - 21); }

__global__ void k_tables(const float* __restrict__ thrx, const float* __restrict__ thrt,
                         float2* __restrict__ W1, float2* __restrict__ qx, float2* __restrict__ qt) {
    int t = threadIdx.x;
    if (t < 128) {
        float s, c;
        float ang = -TWO_PI * (float)t * (1.0f / 128.0f);
        sincosf(ang, &s, &c);
        W1[t] = make_float2(c, s);
    }
    for (int idx = t; idx < 21 * 128; idx += 256) {
        int i = idx >> 7, n = idx & 127;
        float k = kfreq(i), fn = (float)n;
        float s, c;
        {
            float raw = thrx[i];
            float sig = 1.0f / (1.0f + expf(-raw));
            float th = (k < 0.0f) ? (0.5f * PI_F) * (1.0f + sig) : PI_F * sig;
            float ka = fabsf(k);
            float amp = expf(-TWO_PI * ka * sinf(th) * fn * (1.0f / 128.0f));
            float a2 = TWO_PI * ka * cosf(th) * fn * (1.0f / 128.0f);
            sincosf(a2, &s, &c);
            qx[idx] = make_float2(amp * c, amp * s);
        }
        {
            float raw = thrt[i];
            float sig = 1.0f / (1.0f + expf(-raw));
            float th = (k < 0.0f) ? (0.5f * PI_F) * (1.0f + sig) : PI_F * sig;
            float ka = fabsf(k);
            float amp = expf(-TWO_PI * ka * sinf(th) * fn * (1.0f / 128.0f));
            float a2 = TWO_PI * ka * cosf(th) * fn * (1.0f / 128.0f);
            sincosf(a2, &s, &c);
            qt[idx] = make_float2(amp * c, amp * s);
        }
    }
}

// ---------------------------------------------------------------- weight transpose [co][ij] -> [ij][co]
__global__ void k_wt(const float* __restrict__ wr, const float* __restrict__ wi,
                     float2* __restrict__ Rt) {
    __shared__ float2 tile[64][65];
    const int tx = threadIdx.x & 63;
    const int ty = threadIdx.x >> 6;
    const int ij0 = blockIdx.x * 64;
    const int co0 = blockIdx.y * 64;
    #pragma unroll
    for (int r = 0; r < 16; ++r) {
        int row = ty + r * 4;
        int col = ij0 + tx;
        if (col < 441) {
            size_t g = (size_t)(co0 + row) * 441 + col;
            tile[row][tx] = make_float2(wr[g], wi[g]);
        }
    }
    __syncthreads();
    #pragma unroll
    for (int r = 0; r < 16; ++r) {
        int row = ty + r * 4;
        int ij = ij0 + row;
        if (ij < 441)
            Rt[(size_t)ij * 4096 + co0 + tx] = tile[tx][row];
    }
}

// ---------------------------------------------------------------- forward DFT (per b,c)
// phase1: T1[n][j] = sum_m x[n][m] W1[(j*m)&127], j=0..10 (+pad j=11)
//   wave w owns j-trio 3w..3w+2; lane owns n-pair (2*lane, 2*lane+1)
// phase2: X[i][j] = sum_n W1[(kk_i*n)&127] T1[n][j]; conj-fill to 441
__launch_bounds__(256, 4)
__global__ void k_fwd(const float* __restrict__ x, const float2* __restrict__ W1,
                      float2* __restrict__ Xb) {
    __shared__ __align__(16) float  xs[32 * 130];    // [m_local][n], 16640 B
    __shared__ __align__(16) float2 t1s[128 * 13];   // [n][j], cols 11,12 pad, 13312 B
    __shared__ __align__(16) float2 W1s[512];        // W1 replicated 4x, 4096 B
    __shared__ float2 xout[231];
    const int t = threadIdx.x;
    const int bc = blockIdx.x;
    const int lane = t & 63;
    const int w = t >> 6;
    const int jb = 3 * w;                 // j = jb..jb+2 (w=3 -> j=11 is pad)
    const int n0 = 2 * lane;

    {   // stage W1 4x replicated
        float4 v = reinterpret_cast<const float4*>(W1)[t & 63];
        reinterpret_cast<float4*>(W1s)[t] = v;
    }

    float ar[3][2], ai[3][2];
    #pragma unroll
    for (int jj = 0; jj < 3; ++jj) { ar[jj][0] = ar[jj][1] = ai[jj][0] = ai[jj][1] = 0.f; }

    const float* xg = x + (size_t)bc * 16384;
    const char* W1b = reinterpret_cast<const char*>(W1s);
    for (int ch = 0; ch < 4; ++ch) {
        __syncthreads();
        #pragma unroll
        for (int pass = 0; pass < 4; ++pass) {      // stage 128 rows x 32 cols -> xs[m][n]
            int fid = pass * 256 + t;
            int row = fid >> 3, f = fid & 7;
            float4 v = *reinterpret_cast<const float4*>(xg + row * 128 + ch * 32 + f * 4);
            xs[(f * 4 + 0) * 130 + row] = v.x;
            xs[(f * 4 + 1) * 130 + row] = v.y;
            xs[(f * 4 + 2) * 130 + row] = v.z;
            xs[(f * 4 + 3) * 130 + row] = v.w;
        }
        __syncthreads();
        // byte offsets into W1s at m = ch*32 for j = jb..jb+2
        int ib0 = (((jb + 0) * ch * 32) & 127) * 8;
        int ib1 = (((jb + 1) * ch * 32) & 127) * 8;
        int ib2 = (((jb + 2) * ch * 32) & 127) * 8;
        #pragma unroll
        for (int mm = 0; mm < 32; ++mm) {
            float2 xv  = *reinterpret_cast<const float2*>(&xs[mm * 130 + n0]);
            float2 w0  = *reinterpret_cast<const float2*>(W1b + ib0);
            float2 w1v = *reinterpret_cast<const float2*>(W1b + ib1);
            float2 w2v = *reinterpret_cast<const float2*>(W1b + ib2);
            ar[0][0] += xv.x * w0.x;  ai[0][0] += xv.x * w0.y;
            ar[0][1] += xv.y * w0.x;  ai[0][1] += xv.y * w0.y;
            ar[1][0] += xv.x * w1v.x; ai[1][0] += xv.x * w1v.y;
            ar[1][1] += xv.y * w1v.x; ai[1][1] += xv.y * w1v.y;
            ar[2][0] += xv.x * w2v.x; ai[2][0] += xv.x * w2v.y;
            ar[2][1] += xv.y * w2v.x; ai[2][1] += xv.y * w2v.y;
            ib0 += (jb + 0) * 8;      // stays < 4096 within one ch (4x replication)
            ib1 += (jb + 1) * 8;
            ib2 += (jb + 2) * 8;
        }
    }
    #pragma unroll
    for (int jj = 0; jj < 3; ++jj) {
        t1s[(n0 + 0) * 13 + jb + jj] = make_float2(ar[jj][0], ai[jj][0]);
        t1s[(n0 + 1) * 13 + jb + jj] = make_float2(ar[jj][1], ai[jj][1]);
    }
    __syncthreads();
    if (t < 231) {
        int i = t / 11, j = t % 11;
        int kk = (i <= 10) ? i : i + 107;   // k_i mod 128
        int ib = 0;
        float are = 0.f, aim = 0.f;
        for (int nn = 0; nn < 128; ++nn) {
            float2 pv = *reinterpret_cast<const float2*>(W1b + ib);
            float2 tv = t1s[nn * 13 + j];
            are += pv.x * tv.x - pv.y * tv.y;
            aim += pv.x * tv.y + pv.y * tv.x;
            ib = (ib + kk * 8) & 1023;
        }
        xout[i * 11 + j] = make_float2(are * NORM, aim * NORM);
    }
    __syncthreads();
    for (int p = t; p < 441; p += 256) {
        int i = p / 21, j = p % 21;
        float2 v;
        if (j < 11) v = xout[i * 11 + j];
        else {
            float2 u = xout[((21 - i) % 21) * 11 + (21 - j)];
            v = make_float2(u.x, -u.y);
        }
        Xb[(size_t)bc * 448 + p] = v;
    }
}

// ---------------------------------------------------------------- channel mix (per mode) [unchanged]
__launch_bounds__(256, 2)
__global__ void k_mix(const float2* __restrict__ Xg, const float2* __restrict__ Rt,
                      float2* __restrict__ OK) {
    __shared__ float2 Xs[2048];
    __shared__ float2 Rs[4096];
    int t = threadIdx.x;
    int ij = blockIdx.x;
    for (int k = t; k < 2048; k += 256) Xs[k] = Xg[(size_t)k * 448 + ij];
    for (int k = t; k < 4096; k += 256) Rs[k] = Rt[(size_t)ij * 4096 + k];
    __syncthreads();
    int o = t & 63, bg = t >> 6;
    float accre[8], accim[8];
    #pragma unroll
    for (int i = 0; i < 8; ++i) { accre[i] = 0.f; accim[i] = 0.f; }
    for (int c = 0; c < 64; ++c) {
        float2 rv = Rs[c * 64 + o];
        #pragma unroll
        for (int bb = 0; bb < 8; ++bb) {
            float2 xv = Xs[(bg * 8 + bb) * 64 + c];
            accre[bb] += xv.x * rv.x - xv.y * rv.y;
            accim[bb] += xv.x * rv.y + xv.y * rv.x;
        }
    }
    #pragma unroll
    for (int bb = 0; bb < 8; ++bb)
        OK[(size_t)ij * 2048 + (bg * 8 + bb) * 64 + o] = make_float2(accre[bb], accim[bb]);
}

// ---------------------------------------------------------------- inverse DFT (per b,o) [unchanged]
__launch_bounds__(256, 3)
__global__ void k_inv(const float2* __restrict__ OKg, const float2* __restrict__ qx,
                      const float2* __restrict__ qt, float* __restrict__ out) {
    __shared__ __align__(16) float2 qs[21 * 130];
    __shared__ __align__(16) float2 t2s[21 * 130];
    __shared__ float2 oks[441];
    const int t = threadIdx.x;
    const int bo = blockIdx.x;

    for (int k = t; k < 441; k += 256) oks[k] = OKg[(size_t)k * 2048 + bo];
    for (int k = t; k < 1344; k += 256) {
        int row = k >> 6, c4 = k & 63;
        reinterpret_cast<float4*>(qs + row * 130)[c4] =
            reinterpret_cast<const float4*>(qx + row * 128)[c4];
    }
    __syncthreads();
    {
        const int ng = t & 31, jg = t >> 5;
        const int jbase = (jg < 5) ? 3 * jg : 15 + 2 * (jg - 5);
        const int jcnt  = (jg < 5) ? 3 : 2;
        float are[4][3], aim[4][3];
        #pragma unroll
        for (int r = 0; r < 4; ++r)
            #pragma unroll
            for (int jj = 0; jj < 3; ++jj) { are[r][jj] = 0.f; aim[r][jj] = 0.f; }
        for (int i = 0; i < 21; ++i) {
            float2 q0 = qs[i * 130 + ng];
            float2 q1 = qs[i * 130 + ng + 32];
            float2 q2 = qs[i * 130 + ng + 64];
            float2 q3 = qs[i * 130 + ng + 96];
            #pragma unroll
            for (int jj = 0; jj < 3; ++jj) {
                if (jj < jcnt) {
                    float2 okv = oks[i * 21 + jbase + jj];
                    are[0][jj] += okv.x * q0.x - okv.y * q0.y;
                    aim[0][jj] += okv.x * q0.y + okv.y * q0.x;
                    are[1][jj] += okv.x * q1.x - okv.y * q1.y;
                    aim[1][jj] += okv.x * q1.y + okv.y * q1.x;
                    are[2][jj] += okv.x * q2.x - okv.y * q2.y;
                    aim[2][jj] += okv.x * q2.y + okv.y * q2.x;
                    are[3][jj] += okv.x * q3.x - okv.y * q3.y;
                    aim[3][jj] += okv.x * q3.y + okv.y * q3.x;
                }
            }
        }
        #pragma unroll
        for (int jj = 0; jj < 3; ++jj) {
            if (jj < jcnt) {
                #pragma unroll
                for (int r = 0; r < 4; ++r)
                    t2s[(jbase + jj) * 130 + ng + 32 * r] = make_float2(are[r][jj], aim[r][jj]);
            }
        }
    }
    __syncthreads();
    for (int k = t; k < 1344; k += 256) {
        int row = k >> 6, c4 = k & 63;
        reinterpret_cast<float4*>(qs + row * 130)[c4] =
            reinterpret_cast<const float4*>(qt + row * 128)[c4];
    }
    __syncthreads();
    {
        const int lane = t & 63, w = t >> 6;
        const int ml = lane & 31;
        const int nh = lane >> 5;
        const int nbase = w * 32 + nh * 16;
        float acc[16][4];
        #pragma unroll
        for (int r = 0; r < 16; ++r)
            #pragma unroll
            for (int q = 0; q < 4; ++q) acc[r][q] = 0.f;
        for (int j = 0; j < 21; ++j) {
            float2 q0 = qs[j * 130 + ml];
            float2 q1 = qs[j * 130 + ml + 32];
            float2 q2 = qs[j * 130 + ml + 64];
            float2 q3 = qs[j * 130 + ml + 96];
            #pragma unroll
            for (int r = 0; r < 16; ++r) {
                float2 tv = t2s[j * 130 + nbase + r];
                acc[r][0] += tv.x * q0.x - tv.y * q0.y;
                acc[r][1] += tv.x * q1.x - tv.y * q1.y;
                acc[r][2] += tv.x * q2.x - tv.y * q2.y;
                acc[r][3] += tv.x * q3.x - tv.y * q3.y;
            }
        }
        float* og = out + (size_t)bo * 16384;
        #pragma unroll
        for (int r = 0; r < 16; ++r) {
            #pragma unroll
            for (int q = 0; q < 4; ++q)
                og[(nbase + r) * 128 + ml + 32 * q] = acc[r][q] * NORM;
        }
    }
}

// ---------------------------------------------------------------- launch
extern "C" void kernel_launch(void* const* d_in, const int* in_sizes, int n_in,
                              void* d_out, int out_size, void* d_ws, size_t ws_size,
                              hipStream_t stream) {
    const float* x   = (const float*)d_in[0];
    const float* wr  = (const float*)d_in[1];
    const float* wi  = (const float*)d_in[2];
    const float* thx = (const float*)d_in[3];
    const float* tht = (const float*)d_in[4];
    float* out = (float*)d_out;

    char* ws = (char*)d_ws;
    float2* W1 = (float2*)(ws);                                   // 1024 B (slot padded to 21504)
    float2* qx = (float2*)(ws + 21504);                           // 21504 B
    float2* qt = (float2*)(ws + 43008);                           // 21504 B
    float2* Rt = (float2*)(ws + 64512);                           // 14450688 B
    float2* Xb = (float2*)(ws + 64512 + 14450688);                // [2048][448] f2 = 7340032 B
    float2* OK = (float2*)(ws + 64512 + 14450688 + 7340032);      // [441][2048] f2 = 7225344 B

    k_tables<<<1, 256, 0, stream>>>(thx, tht, W1, qx, qt);
    k_wt<<<dim3(7, 64), 256, 0, stream>>>(wr, wi, Rt);
    k_fwd<<<2048, 256, 0, stream>>>(x, W1, Xb);
    k_mix<<<441, 256, 0, stream>>>(Xb, Rt, OK);
    k_inv<<<2048, 256, 0, stream>>>(OK, qx, qt, out);
}